// Round 15
// baseline (217.757 us; speedup 1.0000x reference)
//
#include <hip/hip_runtime.h>

#define N_NODES 50000
#define E_EDGES 800000
#define CIN     32
#define COUT    64
#define NB      16       // cell buckets
#define BCAP    54016    // per-bucket record capacity (avg 50000, +18 sigma)
#define NSHARD  4        // degree-counter shards
#define KPAD    136      // 128 bf16 + 8 pad
#define SCANB   1024
#define NSCANBLK ((N_NODES + SCANB - 1) / SCANB)   // 49
#define MSGCAP  800016   // full-E msg slots
#define EPB     8        // edges per thread in build_recs
#define BBLK    ((E_EDGES + EPB * 256 - 1) / (EPB * 256))   // 391 blocks

typedef __attribute__((ext_vector_type(8))) short s8v;   // 8 bf16 = 4 VGPRs
typedef __attribute__((ext_vector_type(4))) float f4v;
typedef __attribute__((ext_vector_type(4))) unsigned short u4v;

static __device__ inline unsigned short f2bf(float f) {  // RTNE fp32->bf16
    unsigned u = __builtin_bit_cast(unsigned, f);
    u += 0x7fff + ((u >> 16) & 1);
    return (unsigned short)(u >> 16);
}
static __device__ inline float bf2f(unsigned short h) {
    unsigned u = ((unsigned)h) << 16;
    return __builtin_bit_cast(float, u);
}
// packed RTNE pair (manual, no hip_bf16.h dependency)
static __device__ inline unsigned f2bf2(float a, float b) {
    return (unsigned)f2bf(a) | ((unsigned)f2bf(b) << 16);
}

// ================= main (record/CSR, single-pass) path =================

// x (fp32) -> xbf (bf16)
__global__ __launch_bounds__(256) void x2bf_kernel(
    const float* __restrict__ x, unsigned short* __restrict__ xbf)
{
    const int i = blockIdx.x * 256 + threadIdx.x;
    const int total = N_NODES * CIN / 4;
    if (i < total) {
        f4v v = *(const f4v*)(x + (size_t)i * 4);
        union { unsigned u2[2]; u4v v4; } o;
        o.u2[0] = f2bf2(v[0], v[1]);
        o.u2[1] = f2bf2(v[2], v[3]);
        *(u4v*)(xbf + (size_t)i * 4) = o.v4;
    }
}

// fused pass: build cell-bucketed 8B records + sharded degree count.
// rec = row:16 | col:16 | f0q:16 | f1q:16. ONE cursor atomic per bucket per
// block (391 serial RMW/address -- R11 confirmed depth was the wall).
__global__ __launch_bounds__(256) void build_recs(
    const int* __restrict__ ei, const float* __restrict__ pseudo,
    int* __restrict__ cursor, unsigned long long* __restrict__ recs,
    int* __restrict__ degi4)
{
    __shared__ int lh[NB];
    __shared__ int lbase[NB];
    if (threadIdx.x < NB) lh[threadIdx.x] = 0;
    __syncthreads();

    int* __restrict__ dshard = degi4 + (size_t)(blockIdx.x & (NSHARD - 1)) * N_NODES;
    const int ebase0 = blockIdx.x * (EPB * 256);

    unsigned long long rcache[EPB];
    int pcache[EPB];   // b | myoff<<8

#pragma unroll
    for (int i = 0; i < EPB; ++i) {
        const int e = ebase0 + i * 256 + threadIdx.x;
        pcache[i] = -1;
        if (e < E_EDGES) {
            const int row = min(max(ei[e], 0), N_NODES - 1);
            const int col = min(max(ei[E_EDGES + e], 0), N_NODES - 1);
            const float v0 = pseudo[2 * e] * 4.0f, v1 = pseudo[2 * e + 1] * 4.0f;
            const float fl0 = floorf(v0), fl1 = floorf(v1);
            const int lo0 = min(max((int)fl0, 0), 3);
            const int lo1 = min(max((int)fl1, 0), 3);
            const int f0q = min((int)((v0 - fl0) * 65536.0f), 65535);
            const int f1q = min((int)((v1 - fl1) * 65536.0f), 65535);
            const int b = lo0 + 4 * lo1;
            rcache[i] = (unsigned long long)row
                      | ((unsigned long long)col << 16)
                      | ((unsigned long long)f0q << 32)
                      | ((unsigned long long)f1q << 48);
            const int myoff = atomicAdd(&lh[b], 1);
            pcache[i] = b | (myoff << 8);
            atomicAdd(&dshard[row], 1);     // scattered: ~16 RMW/addr, cheap
        }
    }
    __syncthreads();

    if (threadIdx.x < NB)
        lbase[threadIdx.x] = atomicAdd(&cursor[threadIdx.x], lh[threadIdx.x]);
    __syncthreads();

#pragma unroll
    for (int i = 0; i < EPB; ++i) {
        if (pcache[i] >= 0) {
            const int b = pcache[i] & 0xFF;
            const int myoff = pcache[i] >> 8;
            const int idx = min(lbase[b] + myoff, BCAP - 1);   // defensive
            recs[(size_t)b * BCAP + idx] = rcache[i];
        }
    }
}

// pass B1: per-block local exclusive scan of sum-of-shards
__global__ __launch_bounds__(1024) void scan_blocks(
    const int* __restrict__ degi4, int* __restrict__ rowstart, int* __restrict__ bsum)
{
    __shared__ int wsum[16];
    __shared__ int woff[16];
    const int tid = threadIdx.x, lane = tid & 63, wid = tid >> 6;
    const int n = blockIdx.x * SCANB + tid;
    int v = 0;
    if (n < N_NODES) {
#pragma unroll
        for (int s = 0; s < NSHARD; ++s)
            v += degi4[(size_t)s * N_NODES + n];
    }
    int val = v;
#pragma unroll
    for (int off = 1; off < 64; off <<= 1) {
        int t = __shfl_up(val, off);
        if (lane >= off) val += t;
    }
    if (lane == 63) wsum[wid] = val;
    __syncthreads();
    if (tid == 0) {
        int a = 0;
#pragma unroll
        for (int w = 0; w < 16; ++w) { woff[w] = a; a += wsum[w]; }
        bsum[blockIdx.x] = a;
    }
    __syncthreads();
    if (n < N_NODES) rowstart[n] = woff[wid] + (val - v);
}

// pass B2: each block self-computes its bsum prefix and adds it
__global__ __launch_bounds__(1024) void scan_finish(
    int* __restrict__ rowstart, const int* __restrict__ bsum)
{
    const int b = blockIdx.x;
    int off = 0;
    for (int i = 0; i < NSCANBLK; ++i)
        off += (i < b) ? bsum[i] : 0;
    const int n = b * SCANB + threadIdx.x;
    if (n < N_NODES) rowstart[n] += off;
    if (b == NSCANBLK - 1 && threadIdx.x == 0)
        rowstart[N_NODES] = off + bsum[NSCANBLK - 1];
}

// pass D: per-cell MFMA (R12 structure: scaled X' staging, K=128, acc[4],
// 52 VGPR / 33% occupancy). R14b: nontemporal msg stores (no-reuse stream).
__global__ __launch_bounds__(256, 2) void bucket_mfma_rec(
    const unsigned short* __restrict__ xbf, const float* __restrict__ weight,
    const unsigned long long* __restrict__ recs,
    const int* __restrict__ cursor,
    const int* __restrict__ rowstart, int* __restrict__ rcur,
    unsigned short* __restrict__ msg)
{
    __shared__ short XS[4][16 * KPAD];

    const int lane = threadIdx.x & 63;
    const int wid  = threadIdx.x >> 6;
    const int cell = blockIdx.x & (NB - 1);
    const int wGlob   = (blockIdx.x >> 4) * 4 + wid;
    const int wStride = (gridDim.x >> 4) * 4;

    const int lo0 = cell & 3, lo1 = cell >> 2;
    const int base = lo0 + 5 * lo1;
    const int offs[4] = {0, 1, 5, 6};
    const int q = lane >> 4;
    const int c = lane & 15;

    // B-fragments: Wstack[k=s*32+q*8+j][o=nt*16+c]
    s8v bfr[4][4];
#pragma unroll
    for (int s = 0; s < 4; ++s) {
        const float* wp = weight + (size_t)(base + offs[s]) * (CIN * COUT);
#pragma unroll
        for (int nt = 0; nt < 4; ++nt) {
            union { unsigned short u[8]; s8v v; } tmp;
#pragma unroll
            for (int j = 0; j < 8; ++j)
                tmp.u[j] = f2bf(wp[(q * 8 + j) * COUT + nt * 16 + c]);
            bfr[s][nt] = tmp.v;
        }
    }

    const unsigned long long* brec = recs + (size_t)cell * BCAP;
    const int cnt    = min(cursor[cell], BCAP);
    const int ntiles = (cnt + 15) >> 4;

    for (int t = wGlob; t < ntiles; t += wStride) {
        const int ebase = t * 16;

        int colv = 0, slotv = 0;
        float b0 = 0.f, b1 = 0.f, b2 = 0.f, b3 = 0.f;
        if (lane < 16 && (ebase + lane) < cnt) {
            const unsigned long long rec = brec[ebase + lane];   // sequential
            const int row = (int)(rec & 0xFFFF);
            colv = (int)((rec >> 16) & 0xFFFF);
            const float f0 = (float)(int)((rec >> 32) & 0xFFFF) * (1.0f / 65536.0f);
            const float f1 = (float)(int)((rec >> 48) & 0xFFFF) * (1.0f / 65536.0f);
            const int rs = rowstart[row], re = rowstart[row + 1];   // L2-resident
            const float invd = 1.0f / (float)max(re - rs, 1);
            b0 = (1.0f - f0) * (1.0f - f1) * invd;
            b1 = f0 * (1.0f - f1) * invd;
            b2 = (1.0f - f0) * f1 * invd;
            b3 = f0 * f1 * invd;
            slotv = rs + atomicAdd(&rcur[row], 1);   // ~16 RMW/addr, cheap
        }

        // gather (bf16, one 64B line/row) + scale + stage X' (16 x 128 bf16)
        {
            const int eg = lane >> 2, part = lane & 3;
            const int  gc = __shfl(colv, eg);
            const float ss0 = __shfl(b0, eg), ss1 = __shfl(b1, eg);
            const float ss2 = __shfl(b2, eg), ss3 = __shfl(b3, eg);
            const float ss[4] = {ss0, ss1, ss2, ss3};
            union { unsigned short u[8]; s8v v; } xin;
            xin.v = *(const s8v*)(xbf + (size_t)gc * CIN + part * 8);
            float xv[8];
#pragma unroll
            for (int j = 0; j < 8; ++j) xv[j] = bf2f(xin.u[j]);
            short* dst = &XS[wid][eg * KPAD + part * 8];
#pragma unroll
            for (int s = 0; s < 4; ++s) {
                union { unsigned u2[4]; s8v v; } tmp;
#pragma unroll
                for (int j = 0; j < 8; j += 2)
                    tmp.u2[j >> 1] = f2bf2(ss[s] * xv[j], ss[s] * xv[j + 1]);
                *(s8v*)(dst + s * 32) = tmp.v;
            }
        }
        __builtin_amdgcn_wave_barrier();

        s8v afr[4];
        {
            const short* ap = &XS[wid][c * KPAD + q * 8];
#pragma unroll
            for (int ks = 0; ks < 4; ++ks)
                afr[ks] = *(const s8v*)(ap + ks * 32);
        }
        __builtin_amdgcn_wave_barrier();

        f4v acc[4];
#pragma unroll
        for (int nt = 0; nt < 4; ++nt) {
            acc[nt] = (f4v){0.f, 0.f, 0.f, 0.f};
#pragma unroll
            for (int ks = 0; ks < 4; ++ks)
                acc[nt] = __builtin_amdgcn_mfma_f32_16x16x32_bf16(
                    afr[ks], bfr[ks][nt], acc[nt], 0, 0, 0);
        }

        // epilogue: acc -> bf16 tile in LDS, coalesced 128B store per edge
#pragma unroll
        for (int r = 0; r < 4; ++r) {
            const int m = q * 4 + r;
#pragma unroll
            for (int nt = 0; nt < 4; ++nt)
                XS[wid][m * 64 + nt * 16 + c] = (short)f2bf(acc[nt][r]);
        }
        __builtin_amdgcn_wave_barrier();
        {
            const int m2 = lane >> 2;
            int slot2 = __shfl(slotv, m2);
            const bool valid2 = (ebase + m2) < cnt;
            slot2 = min(slot2, MSGCAP - 1);   // defensive
            const short* sp = &XS[wid][m2 * 64 + (lane & 3) * 16];
            s8v vlo = *(const s8v*)sp;
            s8v vhi = *(const s8v*)(sp + 8);
            if (valid2) {
                unsigned short* dst = msg + (size_t)slot2 * COUT + (lane & 3) * 16;
                __builtin_nontemporal_store(vlo, (s8v*)dst);       // no-reuse
                __builtin_nontemporal_store(vhi, (s8v*)(dst + 8)); // stream
            }
        }
        __builtin_amdgcn_wave_barrier();
    }
}

// pass E: per-node segment sum (msg pre-scaled by 1/deg) + root/bias fuse
__global__ __launch_bounds__(256) void gather_sum(
    const unsigned short* __restrict__ msg, const int* __restrict__ rowstart,
    const float* __restrict__ x, const float* __restrict__ root,
    const float* __restrict__ bias, float* __restrict__ out)
{
    const int wave   = (blockIdx.x * blockDim.x + threadIdx.x) >> 6;
    const int lane   = threadIdx.x & 63;
    const int nwaves = (gridDim.x * blockDim.x) >> 6;

    for (int n = wave; n < N_NODES; n += nwaves) {
        const int s  = rowstart[n];
        const int e2 = rowstart[n + 1];
        float acc = 0.f;
#pragma unroll 8
        for (int p = s; p < e2; ++p)
            acc += bf2f(__builtin_nontemporal_load(msg + (size_t)p * COUT + lane));
        const float* xp = x + (size_t)n * CIN;
        float rt = bias[lane];
#pragma unroll
        for (int i = 0; i < CIN; ++i)
            rt += xp[i] * root[i * COUT + lane];
        __builtin_nontemporal_store(acc + rt, out + (size_t)n * COUT + lane);
    }
}

// ================= fallback (R4 atomic) path =================

__global__ __launch_bounds__(256) void count_fb(
    const int* __restrict__ ei, const float* __restrict__ pseudo,
    int* __restrict__ hist, float* __restrict__ deg)
{
    __shared__ int lh[16];
    if (threadIdx.x < 16) lh[threadIdx.x] = 0;
    __syncthreads();
    const int e = blockIdx.x * 256 + threadIdx.x;
    if (e < E_EDGES) {
        int row = min(max(ei[e], 0), N_NODES - 1);
        const float v0 = pseudo[2 * e] * 4.0f, v1 = pseudo[2 * e + 1] * 4.0f;
        const int lo0 = min(max((int)floorf(v0), 0), 3);
        const int lo1 = min(max((int)floorf(v1), 0), 3);
        atomicAdd(&lh[lo0 + 4 * lo1], 1);
        atomicAdd(&deg[row], 1.0f);
    }
    __syncthreads();
    if (threadIdx.x < 16) atomicAdd(&hist[threadIdx.x], lh[threadIdx.x]);
}

__global__ void scan16_fb(const int* __restrict__ hist,
                          int* __restrict__ bstart, int* __restrict__ cursor)
{
    if (threadIdx.x == 0 && blockIdx.x == 0) {
        int acc = 0;
        for (int c = 0; c < 16; ++c) { bstart[c] = acc; cursor[c] = acc; acc += hist[c]; }
    }
}

__global__ __launch_bounds__(256) void scatter_fb(
    const float* __restrict__ pseudo, int* __restrict__ cursor, int* __restrict__ list)
{
    __shared__ int lh[16];
    __shared__ int lbase[16];
    if (threadIdx.x < 16) lh[threadIdx.x] = 0;
    __syncthreads();
    const int e = blockIdx.x * 256 + threadIdx.x;
    int cell = 0, myoff = 0;
    if (e < E_EDGES) {
        const float v0 = pseudo[2 * e] * 4.0f, v1 = pseudo[2 * e + 1] * 4.0f;
        const int lo0 = min(max((int)floorf(v0), 0), 3);
        const int lo1 = min(max((int)floorf(v1), 0), 3);
        cell = lo0 + 4 * lo1;
        myoff = atomicAdd(&lh[cell], 1);
    }
    __syncthreads();
    if (threadIdx.x < 16)
        lbase[threadIdx.x] = atomicAdd(&cursor[threadIdx.x], lh[threadIdx.x]);
    __syncthreads();
    if (e < E_EDGES)
        list[lbase[cell] + myoff] = e;
}

__global__ __launch_bounds__(256, 2) void bucket_mfma_fb(
    const float* __restrict__ x, const int* __restrict__ ei,
    const float* __restrict__ pseudo, const float* __restrict__ weight,
    const int* __restrict__ list, const int* __restrict__ bstart,
    const int* __restrict__ hist, float* __restrict__ out)
{
    __shared__ short XS[4][16 * KPAD];
    const int lane = threadIdx.x & 63;
    const int wid  = threadIdx.x >> 6;
    const int beta = blockIdx.x & 15;
    const int wGlob   = (blockIdx.x >> 4) * 4 + wid;
    const int wStride = (gridDim.x >> 4) * 4;
    const int lo0 = beta & 3, lo1 = beta >> 2;
    const int base = lo0 + 5 * lo1;
    const int offs[4] = {0, 1, 5, 6};
    const int q = lane >> 4, c = lane & 15;

    s8v bfr[4][4];
#pragma unroll
    for (int s = 0; s < 4; ++s) {
        const float* wp = weight + (size_t)(base + offs[s]) * (CIN * COUT);
#pragma unroll
        for (int nt = 0; nt < 4; ++nt) {
            union { unsigned short u[8]; s8v v; } tmp;
#pragma unroll
            for (int j = 0; j < 8; ++j)
                tmp.u[j] = f2bf(wp[(q * 8 + j) * COUT + nt * 16 + c]);
            bfr[s][nt] = tmp.v;
        }
    }
    const int start = bstart[beta], cnt = hist[beta];
    const int ntiles = (cnt + 15) >> 4;

    for (int t = wGlob; t < ntiles; t += wStride) {
        const int ebase = start + t * 16;
        int rowv = 0, colv = 0;
        float b0 = 0.f, b1 = 0.f, b2 = 0.f, b3 = 0.f;
        if (lane < 16 && (t * 16 + lane) < cnt) {
            const int e = list[ebase + lane];
            rowv = min(max(ei[e], 0), N_NODES - 1);
            colv = min(max(ei[E_EDGES + e], 0), N_NODES - 1);
            const float v0 = pseudo[2 * e] * 4.0f, v1 = pseudo[2 * e + 1] * 4.0f;
            const float f0 = v0 - floorf(v0), f1 = v1 - floorf(v1);
            b0 = (1.0f - f0) * (1.0f - f1);
            b1 = f0 * (1.0f - f1);
            b2 = (1.0f - f0) * f1;
            b3 = f0 * f1;
        }
        {
            const int eg = lane >> 2, part = lane & 3;
            const int  gc = __shfl(colv, eg);
            const float ss0 = __shfl(b0, eg), ss1 = __shfl(b1, eg);
            const float ss2 = __shfl(b2, eg), ss3 = __shfl(b3, eg);
            const float ss[4] = {ss0, ss1, ss2, ss3};
            const float* xp = x + (size_t)gc * CIN + part * 8;
            float xv[8];
            *(f4v*)&xv[0] = *(const f4v*)xp;
            *(f4v*)&xv[4] = *(const f4v*)(xp + 4);
            short* dst = &XS[wid][eg * KPAD + part * 8];
#pragma unroll
            for (int s = 0; s < 4; ++s) {
                union { unsigned short u[8]; s8v v; } tmp;
#pragma unroll
                for (int j = 0; j < 8; ++j)
                    tmp.u[j] = f2bf(ss[s] * xv[j]);
                *(s8v*)(dst + s * 32) = tmp.v;
            }
        }
        __builtin_amdgcn_wave_barrier();
        s8v afr[4];
        {
            const short* ap = &XS[wid][c * KPAD + q * 8];
#pragma unroll
            for (int ks = 0; ks < 4; ++ks)
                afr[ks] = *(const s8v*)(ap + ks * 32);
        }
        __builtin_amdgcn_wave_barrier();
        f4v acc[4];
#pragma unroll
        for (int nt = 0; nt < 4; ++nt) {
            acc[nt] = (f4v){0.f, 0.f, 0.f, 0.f};
#pragma unroll
            for (int ks = 0; ks < 4; ++ks)
                acc[nt] = __builtin_amdgcn_mfma_f32_16x16x32_bf16(
                    afr[ks], bfr[ks][nt], acc[nt], 0, 0, 0);
        }
#pragma unroll
        for (int r = 0; r < 4; ++r) {
            const int m = q * 4 + r;
            const int orow = __shfl(rowv, m);
#pragma unroll
            for (int nt = 0; nt < 4; ++nt)
                atomicAdd(&out[(size_t)orow * COUT + nt * 16 + c], acc[nt][r]);
        }
    }
}

__global__ __launch_bounds__(256) void final_fb(
    const float* __restrict__ x, const float* __restrict__ root,
    const float* __restrict__ bias, const float* __restrict__ deg,
    float* __restrict__ out)
{
    const int wave   = (blockIdx.x * blockDim.x + threadIdx.x) >> 6;
    const int lane   = threadIdx.x & 63;
    const int nwaves = (gridDim.x * blockDim.x) >> 6;
    for (int n = wave; n < N_NODES; n += nwaves) {
        const float* xp = x + (size_t)n * CIN;
        float acc = bias[lane];
#pragma unroll
        for (int i = 0; i < CIN; ++i)
            acc += xp[i] * root[i * COUT + lane];
        float dg = deg[n];
        dg = dg > 1.0f ? dg : 1.0f;
        const size_t idx = (size_t)n * COUT + lane;
        out[idx] = out[idx] / dg + acc;
    }
}

extern "C" void kernel_launch(void* const* d_in, const int* in_sizes, int n_in,
                              void* d_out, int out_size, void* d_ws, size_t ws_size,
                              hipStream_t stream) {
    const float* x      = (const float*)d_in[0];
    const int*   ei     = (const int*)d_in[1];
    const float* pseudo = (const float*)d_in[2];
    const float* weight = (const float*)d_in[3];
    const float* root   = (const float*)d_in[4];
    const float* bias   = (const float*)d_in[5];
    float* out = (float*)d_out;

    // ws layout (int elements)
    int* wsI = (int*)d_ws;
    int* cursor16 = wsI;                         // 16 (+16 pad)
    int* degi4    = wsI + 32;                    // 4 x 50000
    int* rcur     = wsI + 200032;                // 50000
    int* rowstart = wsI + 250032;                // 50001 (+15 pad)
    int* bsum     = wsI + 300048;                // 64
    // 300112 ints = 1200448 B, 8B-aligned
    unsigned long long* recs = (unsigned long long*)(wsI + 300112);  // 6.91 MB
    unsigned short* xbf = (unsigned short*)((char*)d_ws + 1200448
                        + (size_t)NB * BCAP * 8);                    // 3.2 MB
    unsigned short* msg = (unsigned short*)((char*)xbf
                        + (size_t)N_NODES * CIN * 2);                // 102.4 MB
    const size_t needed = 1200448 + (size_t)NB * BCAP * 8
                        + (size_t)N_NODES * CIN * 2
                        + (size_t)MSGCAP * COUT * 2;  // ~114 MB

    if (ws_size >= needed) {
        (void)hipMemsetAsync(d_ws, 0, (size_t)250032 * 4, stream);  // cursor+degi4+rcur
        x2bf_kernel<<<(N_NODES * CIN / 4 + 255) / 256, 256, 0, stream>>>(x, xbf);
        build_recs <<<BBLK, 256, 0, stream>>>(ei, pseudo, cursor16, recs, degi4);
        scan_blocks<<<NSCANBLK, 1024, 0, stream>>>(degi4, rowstart, bsum);
        scan_finish<<<NSCANBLK, 1024, 0, stream>>>(rowstart, bsum);
        bucket_mfma_rec<<<16 * 128, 256, 0, stream>>>(
            xbf, weight, recs, cursor16, rowstart, rcur, msg);
        gather_sum<<<4096, 256, 0, stream>>>(msg, rowstart, x, root, bias, out);
    } else {
        // R4 fallback layout
        char* w = (char*)d_ws;
        float* degF   = (float*)w;
        int*   histF  = (int*)(w + 200064);
        int*   bstF   = (int*)(w + 200128);
        int*   curF   = (int*)(w + 200192);
        int*   listF  = (int*)(w + 200256);
        const int eblocks = (E_EDGES + 255) / 256;

        (void)hipMemsetAsync(out, 0, sizeof(float) * (size_t)N_NODES * COUT, stream);
        (void)hipMemsetAsync(degF, 0, sizeof(float) * (size_t)N_NODES, stream);
        (void)hipMemsetAsync(histF, 0, 192, stream);

        count_fb      <<<eblocks, 256, 0, stream>>>(ei, pseudo, histF, degF);
        scan16_fb     <<<1, 64, 0, stream>>>(histF, bstF, curF);
        scatter_fb    <<<eblocks, 256, 0, stream>>>(pseudo, curF, listF);
        bucket_mfma_fb<<<16 * 64, 256, 0, stream>>>(x, ei, pseudo, weight, listF,
                                                    bstF, histF, out);
        final_fb      <<<1024, 256, 0, stream>>>(x, root, bias, degF, out);
    }
}

// Round 16
// 202.286 us; speedup vs baseline: 1.0765x; 1.0765x over previous
//
#include <hip/hip_runtime.h>

#define N_NODES 50000
#define E_EDGES 800000
#define CIN     32
#define COUT    64
#define NB      16       // cell buckets
#define BCAP    54016    // per-bucket record capacity (avg 50000, +18 sigma)
#define NSHARD  4        // degree-counter shards
#define KPAD    136      // 128 bf16 + 8 pad
#define SCANB   1024
#define NSCANBLK ((N_NODES + SCANB - 1) / SCANB)   // 49
#define MSGCAP  800016   // full-E msg slots
#define EPB     8        // edges per thread in build_recs
#define BBLK    ((E_EDGES + EPB * 256 - 1) / (EPB * 256))   // 391 blocks
#define XCHUNK  (N_NODES * CIN / 4)                // 400000 f4 chunks

typedef __attribute__((ext_vector_type(8))) short s8v;   // 8 bf16 = 4 VGPRs
typedef __attribute__((ext_vector_type(4))) float f4v;
typedef __attribute__((ext_vector_type(4))) unsigned short u4v;

static __device__ inline unsigned short f2bf(float f) {  // RTNE fp32->bf16
    unsigned u = __builtin_bit_cast(unsigned, f);
    u += 0x7fff + ((u >> 16) & 1);
    return (unsigned short)(u >> 16);
}
static __device__ inline float bf2f(unsigned short h) {
    unsigned u = ((unsigned)h) << 16;
    return __builtin_bit_cast(float, u);
}
static __device__ inline unsigned f2bf2(float a, float b) {
    return (unsigned)f2bf(a) | ((unsigned)f2bf(b) << 16);
}

// ================= main (record/CSR, single-pass) path =================

// fused pass: x->bf16 conversion slice + cell-bucketed 8B records + sharded
// degree count. rec = row:16 | col:16 | f0q:16 | f1q:16. ONE cursor atomic
// per bucket per block (R11: per-address RMW depth was the wall).
__global__ __launch_bounds__(256) void build_recs(
    const float* __restrict__ x, unsigned short* __restrict__ xbf,
    const int* __restrict__ ei, const float* __restrict__ pseudo,
    int* __restrict__ cursor, unsigned long long* __restrict__ recs,
    int* __restrict__ degi4)
{
    // x2bf slice: 391 blocks x 1024 chunks covers 400384 >= 400000
    {
        const int cb = blockIdx.x * 1024;
#pragma unroll
        for (int k = 0; k < 4; ++k) {
            const int i = cb + k * 256 + threadIdx.x;
            if (i < XCHUNK) {
                f4v v = *(const f4v*)(x + (size_t)i * 4);
                union { unsigned u2[2]; u4v v4; } o;
                o.u2[0] = f2bf2(v[0], v[1]);
                o.u2[1] = f2bf2(v[2], v[3]);
                *(u4v*)(xbf + (size_t)i * 4) = o.v4;
            }
        }
    }

    __shared__ int lh[NB];
    __shared__ int lbase[NB];
    if (threadIdx.x < NB) lh[threadIdx.x] = 0;
    __syncthreads();

    int* __restrict__ dshard = degi4 + (size_t)(blockIdx.x & (NSHARD - 1)) * N_NODES;
    const int ebase0 = blockIdx.x * (EPB * 256);

    unsigned long long rcache[EPB];
    int pcache[EPB];   // b | myoff<<8

#pragma unroll
    for (int i = 0; i < EPB; ++i) {
        const int e = ebase0 + i * 256 + threadIdx.x;
        pcache[i] = -1;
        if (e < E_EDGES) {
            const int row = min(max(ei[e], 0), N_NODES - 1);
            const int col = min(max(ei[E_EDGES + e], 0), N_NODES - 1);
            const float v0 = pseudo[2 * e] * 4.0f, v1 = pseudo[2 * e + 1] * 4.0f;
            const float fl0 = floorf(v0), fl1 = floorf(v1);
            const int lo0 = min(max((int)fl0, 0), 3);
            const int lo1 = min(max((int)fl1, 0), 3);
            const int f0q = min((int)((v0 - fl0) * 65536.0f), 65535);
            const int f1q = min((int)((v1 - fl1) * 65536.0f), 65535);
            const int b = lo0 + 4 * lo1;
            rcache[i] = (unsigned long long)row
                      | ((unsigned long long)col << 16)
                      | ((unsigned long long)f0q << 32)
                      | ((unsigned long long)f1q << 48);
            const int myoff = atomicAdd(&lh[b], 1);
            pcache[i] = b | (myoff << 8);
            atomicAdd(&dshard[row], 1);     // scattered: ~16 RMW/addr, cheap
        }
    }
    __syncthreads();

    if (threadIdx.x < NB)
        lbase[threadIdx.x] = atomicAdd(&cursor[threadIdx.x], lh[threadIdx.x]);
    __syncthreads();

#pragma unroll
    for (int i = 0; i < EPB; ++i) {
        if (pcache[i] >= 0) {
            const int b = pcache[i] & 0xFF;
            const int myoff = pcache[i] >> 8;
            const int idx = min(lbase[b] + myoff, BCAP - 1);   // defensive
            recs[(size_t)b * BCAP + idx] = rcache[i];
        }
    }
}

// pass B1: per-block local exclusive scan of sum-of-shards
__global__ __launch_bounds__(1024) void scan_blocks(
    const int* __restrict__ degi4, int* __restrict__ rowstart, int* __restrict__ bsum)
{
    __shared__ int wsum[16];
    __shared__ int woff[16];
    const int tid = threadIdx.x, lane = tid & 63, wid = tid >> 6;
    const int n = blockIdx.x * SCANB + tid;
    int v = 0;
    if (n < N_NODES) {
#pragma unroll
        for (int s = 0; s < NSHARD; ++s)
            v += degi4[(size_t)s * N_NODES + n];
    }
    int val = v;
#pragma unroll
    for (int off = 1; off < 64; off <<= 1) {
        int t = __shfl_up(val, off);
        if (lane >= off) val += t;
    }
    if (lane == 63) wsum[wid] = val;
    __syncthreads();
    if (tid == 0) {
        int a = 0;
#pragma unroll
        for (int w = 0; w < 16; ++w) { woff[w] = a; a += wsum[w]; }
        bsum[blockIdx.x] = a;
    }
    __syncthreads();
    if (n < N_NODES) rowstart[n] = woff[wid] + (val - v);
}

// pass B2: each block self-computes its bsum prefix and adds it
__global__ __launch_bounds__(1024) void scan_finish(
    int* __restrict__ rowstart, const int* __restrict__ bsum)
{
    const int b = blockIdx.x;
    int off = 0;
    for (int i = 0; i < NSCANBLK; ++i)
        off += (i < b) ? bsum[i] : 0;
    const int n = b * SCANB + threadIdx.x;
    if (n < N_NODES) rowstart[n] += off;
    if (b == NSCANBLK - 1 && threadIdx.x == 0)
        rowstart[N_NODES] = off + bsum[NSCANBLK - 1];
}

// pass D: per-cell MFMA, software-pipelined. Per-lane rec loads (no shfl on
// the metadata path); next tile's rec prefetched at iter top (address is
// data-independent); next tile's x-gather issued right after A-frag reads so
// its ~900cyc HBM flight overlaps MFMA + epilogue + next metadata.
__global__ __launch_bounds__(256, 2) void bucket_mfma_rec(
    const unsigned short* __restrict__ xbf, const float* __restrict__ weight,
    const unsigned long long* __restrict__ recs,
    const int* __restrict__ cursor,
    const int* __restrict__ rowstart, int* __restrict__ rcur,
    unsigned short* __restrict__ msg)
{
    __shared__ short XS[4][16 * KPAD];

    const int lane = threadIdx.x & 63;
    const int wid  = threadIdx.x >> 6;
    const int cell = blockIdx.x & (NB - 1);
    const int wGlob   = (blockIdx.x >> 4) * 4 + wid;
    const int wStride = (gridDim.x >> 4) * 4;
    const int eg = lane >> 2, part = lane & 3;   // lane's edge / 8-elem slice

    const int lo0 = cell & 3, lo1 = cell >> 2;
    const int base = lo0 + 5 * lo1;
    const int offs[4] = {0, 1, 5, 6};
    const int q = lane >> 4;
    const int c = lane & 15;

    // B-fragments: Wstack[k=s*32+q*8+j][o=nt*16+c]
    s8v bfr[4][4];
#pragma unroll
    for (int s = 0; s < 4; ++s) {
        const float* wp = weight + (size_t)(base + offs[s]) * (CIN * COUT);
#pragma unroll
        for (int nt = 0; nt < 4; ++nt) {
            union { unsigned short u[8]; s8v v; } tmp;
#pragma unroll
            for (int j = 0; j < 8; ++j)
                tmp.u[j] = f2bf(wp[(q * 8 + j) * COUT + nt * 16 + c]);
            bfr[s][nt] = tmp.v;
        }
    }

    const unsigned long long* brec = recs + (size_t)cell * BCAP;
    const int cnt    = min(cursor[cell], BCAP);
    const int ntiles = (cnt + 15) >> 4;

    // pipeline prologue: rec + x for first tile
    int t = wGlob;
    unsigned long long rec_c = 0;
    s8v x_c = {};
    if (t < ntiles) {
        rec_c = brec[min(t * 16 + eg, cnt - 1)];
        const int col = (int)((rec_c >> 16) & 0xFFFF);
        x_c = *(const s8v*)(xbf + (size_t)col * CIN + part * 8);
    }

    for (; t < ntiles; t += wStride) {
        const int tn = t + wStride;
        unsigned long long rec_n = 0;
        if (tn < ntiles)
            rec_n = brec[min(tn * 16 + eg, cnt - 1)];   // prefetch (L2, no dep)

        // metadata from rec_c (this lane's edge = t*16+eg); no shfl needed
        const bool vcur = (t * 16 + eg) < cnt;
        const int row = (int)(rec_c & 0xFFFF);
        const float f0 = (float)(int)((rec_c >> 32) & 0xFFFF) * (1.0f / 65536.0f);
        const float f1 = (float)(int)((rec_c >> 48) & 0xFFFF) * (1.0f / 65536.0f);
        const int rs = rowstart[row], re = rowstart[row + 1];   // L2-resident
        const float invd = vcur ? (1.0f / (float)max(re - rs, 1)) : 0.0f;
        const float s0 = (1.0f - f0) * (1.0f - f1) * invd;
        const float s1 = f0 * (1.0f - f1) * invd;
        const float s2 = (1.0f - f0) * f1 * invd;
        const float s3 = f0 * f1 * invd;
        int slotv = 0;
        if (vcur && part == 0)
            slotv = rs + atomicAdd(&rcur[row], 1);   // one lane per edge

        // stage scaled X' (16 x 128 bf16) from x_c
        {
            union { unsigned short u[8]; s8v v; } xin; xin.v = x_c;
            float xv[8];
#pragma unroll
            for (int j = 0; j < 8; ++j) xv[j] = bf2f(xin.u[j]);
            short* dst = &XS[wid][eg * KPAD + part * 8];
            const float ss[4] = {s0, s1, s2, s3};
#pragma unroll
            for (int s = 0; s < 4; ++s) {
                union { unsigned u2[4]; s8v v; } tmp;
#pragma unroll
                for (int j = 0; j < 8; j += 2)
                    tmp.u2[j >> 1] = f2bf2(ss[s] * xv[j], ss[s] * xv[j + 1]);
                *(s8v*)(dst + s * 32) = tmp.v;
            }
        }
        __builtin_amdgcn_wave_barrier();

        s8v afr[4];
        {
            const short* ap = &XS[wid][c * KPAD + q * 8];
#pragma unroll
            for (int ks = 0; ks < 4; ++ks)
                afr[ks] = *(const s8v*)(ap + ks * 32);
        }
        __builtin_amdgcn_wave_barrier();

        // issue next tile's x gather NOW: flight overlaps MFMA + epilogue
        s8v x_n = {};
        if (tn < ntiles) {
            const int coln = (int)((rec_n >> 16) & 0xFFFF);
            x_n = *(const s8v*)(xbf + (size_t)coln * CIN + part * 8);
        }

        f4v acc[4];
#pragma unroll
        for (int nt = 0; nt < 4; ++nt) {
            acc[nt] = (f4v){0.f, 0.f, 0.f, 0.f};
#pragma unroll
            for (int ks = 0; ks < 4; ++ks)
                acc[nt] = __builtin_amdgcn_mfma_f32_16x16x32_bf16(
                    afr[ks], bfr[ks][nt], acc[nt], 0, 0, 0);
        }

        // epilogue: acc -> bf16 tile in LDS, coalesced 128B store per edge
#pragma unroll
        for (int r = 0; r < 4; ++r) {
            const int m = q * 4 + r;
#pragma unroll
            for (int nt = 0; nt < 4; ++nt)
                XS[wid][m * 64 + nt * 16 + c] = (short)f2bf(acc[nt][r]);
        }
        __builtin_amdgcn_wave_barrier();
        {
            int slot2 = __shfl(slotv, eg * 4);   // slot lives at lane eg*4
            const bool valid2 = (t * 16 + eg) < cnt;
            slot2 = min(slot2, MSGCAP - 1);      // defensive
            const short* sp = &XS[wid][eg * 64 + part * 16];
            s8v vlo = *(const s8v*)sp;
            s8v vhi = *(const s8v*)(sp + 8);
            if (valid2) {
                unsigned short* dst = msg + (size_t)slot2 * COUT + part * 16;
                *(s8v*)dst = vlo;
                *(s8v*)(dst + 8) = vhi;
            }
        }
        __builtin_amdgcn_wave_barrier();

        rec_c = rec_n;
        x_c   = x_n;
    }
}

// pass E: per-node segment sum (msg pre-scaled by 1/deg) + root/bias fuse
__global__ __launch_bounds__(256) void gather_sum(
    const unsigned short* __restrict__ msg, const int* __restrict__ rowstart,
    const float* __restrict__ x, const float* __restrict__ root,
    const float* __restrict__ bias, float* __restrict__ out)
{
    const int wave   = (blockIdx.x * blockDim.x + threadIdx.x) >> 6;
    const int lane   = threadIdx.x & 63;
    const int nwaves = (gridDim.x * blockDim.x) >> 6;

    for (int n = wave; n < N_NODES; n += nwaves) {
        const int s  = rowstart[n];
        const int e2 = rowstart[n + 1];
        float acc = 0.f;
#pragma unroll 8
        for (int p = s; p < e2; ++p)
            acc += bf2f(msg[(size_t)p * COUT + lane]);
        const float* xp = x + (size_t)n * CIN;
        float rt = bias[lane];
#pragma unroll
        for (int i = 0; i < CIN; ++i)
            rt += xp[i] * root[i * COUT + lane];
        out[(size_t)n * COUT + lane] = acc + rt;
    }
}

// ================= fallback (R4 atomic) path =================

__global__ __launch_bounds__(256) void count_fb(
    const int* __restrict__ ei, const float* __restrict__ pseudo,
    int* __restrict__ hist, float* __restrict__ deg)
{
    __shared__ int lh[16];
    if (threadIdx.x < 16) lh[threadIdx.x] = 0;
    __syncthreads();
    const int e = blockIdx.x * 256 + threadIdx.x;
    if (e < E_EDGES) {
        int row = min(max(ei[e], 0), N_NODES - 1);
        const float v0 = pseudo[2 * e] * 4.0f, v1 = pseudo[2 * e + 1] * 4.0f;
        const int lo0 = min(max((int)floorf(v0), 0), 3);
        const int lo1 = min(max((int)floorf(v1), 0), 3);
        atomicAdd(&lh[lo0 + 4 * lo1], 1);
        atomicAdd(&deg[row], 1.0f);
    }
    __syncthreads();
    if (threadIdx.x < 16) atomicAdd(&hist[threadIdx.x], lh[threadIdx.x]);
}

__global__ void scan16_fb(const int* __restrict__ hist,
                          int* __restrict__ bstart, int* __restrict__ cursor)
{
    if (threadIdx.x == 0 && blockIdx.x == 0) {
        int acc = 0;
        for (int c = 0; c < 16; ++c) { bstart[c] = acc; cursor[c] = acc; acc += hist[c]; }
    }
}

__global__ __launch_bounds__(256) void scatter_fb(
    const float* __restrict__ pseudo, int* __restrict__ cursor, int* __restrict__ list)
{
    __shared__ int lh[16];
    __shared__ int lbase[16];
    if (threadIdx.x < 16) lh[threadIdx.x] = 0;
    __syncthreads();
    const int e = blockIdx.x * 256 + threadIdx.x;
    int cell = 0, myoff = 0;
    if (e < E_EDGES) {
        const float v0 = pseudo[2 * e] * 4.0f, v1 = pseudo[2 * e + 1] * 4.0f;
        const int lo0 = min(max((int)floorf(v0), 0), 3);
        const int lo1 = min(max((int)floorf(v1), 0), 3);
        cell = lo0 + 4 * lo1;
        myoff = atomicAdd(&lh[cell], 1);
    }
    __syncthreads();
    if (threadIdx.x < 16)
        lbase[threadIdx.x] = atomicAdd(&cursor[threadIdx.x], lh[threadIdx.x]);
    __syncthreads();
    if (e < E_EDGES)
        list[lbase[cell] + myoff] = e;
}

__global__ __launch_bounds__(256, 2) void bucket_mfma_fb(
    const float* __restrict__ x, const int* __restrict__ ei,
    const float* __restrict__ pseudo, const float* __restrict__ weight,
    const int* __restrict__ list, const int* __restrict__ bstart,
    const int* __restrict__ hist, float* __restrict__ out)
{
    __shared__ short XS[4][16 * KPAD];
    const int lane = threadIdx.x & 63;
    const int wid  = threadIdx.x >> 6;
    const int beta = blockIdx.x & 15;
    const int wGlob   = (blockIdx.x >> 4) * 4 + wid;
    const int wStride = (gridDim.x >> 4) * 4;
    const int lo0 = beta & 3, lo1 = beta >> 2;
    const int base = lo0 + 5 * lo1;
    const int offs[4] = {0, 1, 5, 6};
    const int q = lane >> 4, c = lane & 15;

    s8v bfr[4][4];
#pragma unroll
    for (int s = 0; s < 4; ++s) {
        const float* wp = weight + (size_t)(base + offs[s]) * (CIN * COUT);
#pragma unroll
        for (int nt = 0; nt < 4; ++nt) {
            union { unsigned short u[8]; s8v v; } tmp;
#pragma unroll
            for (int j = 0; j < 8; ++j)
                tmp.u[j] = f2bf(wp[(q * 8 + j) * COUT + nt * 16 + c]);
            bfr[s][nt] = tmp.v;
        }
    }
    const int start = bstart[beta], cnt = hist[beta];
    const int ntiles = (cnt + 15) >> 4;

    for (int t = wGlob; t < ntiles; t += wStride) {
        const int ebase = start + t * 16;
        int rowv = 0, colv = 0;
        float b0 = 0.f, b1 = 0.f, b2 = 0.f, b3 = 0.f;
        if (lane < 16 && (t * 16 + lane) < cnt) {
            const int e = list[ebase + lane];
            rowv = min(max(ei[e], 0), N_NODES - 1);
            colv = min(max(ei[E_EDGES + e], 0), N_NODES - 1);
            const float v0 = pseudo[2 * e] * 4.0f, v1 = pseudo[2 * e + 1] * 4.0f;
            const float f0 = v0 - floorf(v0), f1 = v1 - floorf(v1);
            b0 = (1.0f - f0) * (1.0f - f1);
            b1 = f0 * (1.0f - f1);
            b2 = (1.0f - f0) * f1;
            b3 = f0 * f1;
        }
        {
            const int eg = lane >> 2, part = lane & 3;
            const int  gc = __shfl(colv, eg);
            const float ss0 = __shfl(b0, eg), ss1 = __shfl(b1, eg);
            const float ss2 = __shfl(b2, eg), ss3 = __shfl(b3, eg);
            const float ss[4] = {ss0, ss1, ss2, ss3};
            const float* xp = x + (size_t)gc * CIN + part * 8;
            float xv[8];
            *(f4v*)&xv[0] = *(const f4v*)xp;
            *(f4v*)&xv[4] = *(const f4v*)(xp + 4);
            short* dst = &XS[wid][eg * KPAD + part * 8];
#pragma unroll
            for (int s = 0; s < 4; ++s) {
                union { unsigned short u[8]; s8v v; } tmp;
#pragma unroll
                for (int j = 0; j < 8; ++j)
                    tmp.u[j] = f2bf(ss[s] * xv[j]);
                *(s8v*)(dst + s * 32) = tmp.v;
            }
        }
        __builtin_amdgcn_wave_barrier();
        s8v afr[4];
        {
            const short* ap = &XS[wid][c * KPAD + q * 8];
#pragma unroll
            for (int ks = 0; ks < 4; ++ks)
                afr[ks] = *(const s8v*)(ap + ks * 32);
        }
        __builtin_amdgcn_wave_barrier();
        f4v acc[4];
#pragma unroll
        for (int nt = 0; nt < 4; ++nt) {
            acc[nt] = (f4v){0.f, 0.f, 0.f, 0.f};
#pragma unroll
            for (int ks = 0; ks < 4; ++ks)
                acc[nt] = __builtin_amdgcn_mfma_f32_16x16x32_bf16(
                    afr[ks], bfr[ks][nt], acc[nt], 0, 0, 0);
        }
#pragma unroll
        for (int r = 0; r < 4; ++r) {
            const int m = q * 4 + r;
            const int orow = __shfl(rowv, m);
#pragma unroll
            for (int nt = 0; nt < 4; ++nt)
                atomicAdd(&out[(size_t)orow * COUT + nt * 16 + c], acc[nt][r]);
        }
    }
}

__global__ __launch_bounds__(256) void final_fb(
    const float* __restrict__ x, const float* __restrict__ root,
    const float* __restrict__ bias, const float* __restrict__ deg,
    float* __restrict__ out)
{
    const int wave   = (blockIdx.x * blockDim.x + threadIdx.x) >> 6;
    const int lane   = threadIdx.x & 63;
    const int nwaves = (gridDim.x * blockDim.x) >> 6;
    for (int n = wave; n < N_NODES; n += nwaves) {
        const float* xp = x + (size_t)n * CIN;
        float acc = bias[lane];
#pragma unroll
        for (int i = 0; i < CIN; ++i)
            acc += xp[i] * root[i * COUT + lane];
        float dg = deg[n];
        dg = dg > 1.0f ? dg : 1.0f;
        const size_t idx = (size_t)n * COUT + lane;
        out[idx] = out[idx] / dg + acc;
    }
}

extern "C" void kernel_launch(void* const* d_in, const int* in_sizes, int n_in,
                              void* d_out, int out_size, void* d_ws, size_t ws_size,
                              hipStream_t stream) {
    const float* x      = (const float*)d_in[0];
    const int*   ei     = (const int*)d_in[1];
    const float* pseudo = (const float*)d_in[2];
    const float* weight = (const float*)d_in[3];
    const float* root   = (const float*)d_in[4];
    const float* bias   = (const float*)d_in[5];
    float* out = (float*)d_out;

    // ws layout (int elements)
    int* wsI = (int*)d_ws;
    int* cursor16 = wsI;                         // 16 (+16 pad)
    int* degi4    = wsI + 32;                    // 4 x 50000
    int* rcur     = wsI + 200032;                // 50000
    int* rowstart = wsI + 250032;                // 50001 (+15 pad)
    int* bsum     = wsI + 300048;                // 64
    // 300112 ints = 1200448 B, 8B-aligned
    unsigned long long* recs = (unsigned long long*)(wsI + 300112);  // 6.91 MB
    unsigned short* xbf = (unsigned short*)((char*)d_ws + 1200448
                        + (size_t)NB * BCAP * 8);                    // 3.2 MB
    unsigned short* msg = (unsigned short*)((char*)xbf
                        + (size_t)N_NODES * CIN * 2);                // 102.4 MB
    const size_t needed = 1200448 + (size_t)NB * BCAP * 8
                        + (size_t)N_NODES * CIN * 2
                        + (size_t)MSGCAP * COUT * 2;  // ~114 MB

    if (ws_size >= needed) {
        (void)hipMemsetAsync(d_ws, 0, (size_t)250032 * 4, stream);  // cursor+degi4+rcur
        build_recs <<<BBLK, 256, 0, stream>>>(x, xbf, ei, pseudo, cursor16, recs, degi4);
        scan_blocks<<<NSCANBLK, 1024, 0, stream>>>(degi4, rowstart, bsum);
        scan_finish<<<NSCANBLK, 1024, 0, stream>>>(rowstart, bsum);
        bucket_mfma_rec<<<16 * 128, 256, 0, stream>>>(
            xbf, weight, recs, cursor16, rowstart, rcur, msg);
        gather_sum<<<4096, 256, 0, stream>>>(msg, rowstart, x, root, bias, out);
    } else {
        // R4 fallback layout
        char* w = (char*)d_ws;
        float* degF   = (float*)w;
        int*   histF  = (int*)(w + 200064);
        int*   bstF   = (int*)(w + 200128);
        int*   curF   = (int*)(w + 200192);
        int*   listF  = (int*)(w + 200256);
        const int eblocks = (E_EDGES + 255) / 256;

        (void)hipMemsetAsync(out, 0, sizeof(float) * (size_t)N_NODES * COUT, stream);
        (void)hipMemsetAsync(degF, 0, sizeof(float) * (size_t)N_NODES, stream);
        (void)hipMemsetAsync(histF, 0, 192, stream);

        count_fb      <<<eblocks, 256, 0, stream>>>(ei, pseudo, histF, degF);
        scan16_fb     <<<1, 64, 0, stream>>>(histF, bstF, curF);
        scatter_fb    <<<eblocks, 256, 0, stream>>>(pseudo, curF, listF);
        bucket_mfma_fb<<<16 * 64, 256, 0, stream>>>(x, ei, pseudo, weight, listF,
                                                    bstF, histF, out);
        final_fb      <<<1024, 256, 0, stream>>>(x, root, bias, degF, out);
    }
}

// Round 17
// 199.537 us; speedup vs baseline: 1.0913x; 1.0138x over previous
//
#include <hip/hip_runtime.h>

#define N_NODES 50000
#define E_EDGES 800000
#define CIN     32
#define COUT    64
#define NB      16       // cell buckets
#define BCAP    54016    // per-bucket rec capacity (16-aligned; avg 50000 +18s)
#define NCB     196      // coarse row buckets (row>>8)
#define RCAP    4864     // per-coarse-bucket capacity (avg 4082 +12s)
#define KPAD    136      // 128 bf16 + 8 pad
#define SCANB   1024
#define NSCANBLK ((N_NODES + SCANB - 1) / SCANB)   // 49
#define EPB     8        // edges per thread in build_recs
#define BBLK    ((E_EDGES + EPB * 256 - 1) / (EPB * 256))   // 391 blocks
#define XCHUNK  (N_NODES * CIN / 4)                // 400000 f4 chunks

typedef __attribute__((ext_vector_type(8))) short s8v;   // 8 bf16 = 4 VGPRs
typedef __attribute__((ext_vector_type(4))) float f4v;
typedef __attribute__((ext_vector_type(4))) unsigned short u4v;

static __device__ inline unsigned short f2bf(float f) {  // RTNE fp32->bf16
    unsigned u = __builtin_bit_cast(unsigned, f);
    u += 0x7fff + ((u >> 16) & 1);
    return (unsigned short)(u >> 16);
}
static __device__ inline float bf2f(unsigned short h) {
    unsigned u = ((unsigned)h) << 16;
    return __builtin_bit_cast(float, u);
}
static __device__ inline unsigned f2bf2(float a, float b) {
    return (unsigned)f2bf(a) | ((unsigned)f2bf(b) << 16);
}

// ============ main path: zero scattered global atomics ============

// fused: x->bf16 slice + cell-bucketed recs + row-coarse (row,recslot) pairs.
// rec = row:16|col:16|f0q:16|f1q:16.  rp entry = recslot:20|rowlow:8.
// Only block-aggregated cursor atomics (391 RMW/addr -- R11-proven cheap).
__global__ __launch_bounds__(256) void build_recs(
    const float* __restrict__ x, unsigned short* __restrict__ xbf,
    const int* __restrict__ ei, const float* __restrict__ pseudo,
    int* __restrict__ cursor, int* __restrict__ cursR,
    unsigned long long* __restrict__ recs, unsigned* __restrict__ rp)
{
    // x2bf slice: 391 blocks x 1024 chunks covers 400384 >= 400000
    {
        const int cb = blockIdx.x * 1024;
#pragma unroll
        for (int k = 0; k < 4; ++k) {
            const int i = cb + k * 256 + threadIdx.x;
            if (i < XCHUNK) {
                f4v v = *(const f4v*)(x + (size_t)i * 4);
                union { unsigned u2[2]; u4v v4; } o;
                o.u2[0] = f2bf2(v[0], v[1]);
                o.u2[1] = f2bf2(v[2], v[3]);
                *(u4v*)(xbf + (size_t)i * 4) = o.v4;
            }
        }
    }

    __shared__ int lh[NB];
    __shared__ int lbase[NB];
    __shared__ int lh2[NCB];
    __shared__ int lbase2[NCB];
    if (threadIdx.x < NB) lh[threadIdx.x] = 0;
    if (threadIdx.x < NCB) lh2[threadIdx.x] = 0;
    __syncthreads();

    const int ebase0 = blockIdx.x * (EPB * 256);
    unsigned long long rcache[EPB];
    int pcache[EPB];    // b | myoff<<8
    int pcache2[EPB];   // cb | myoff2<<8

#pragma unroll
    for (int i = 0; i < EPB; ++i) {
        const int e = ebase0 + i * 256 + threadIdx.x;
        pcache[i] = -1; pcache2[i] = -1;
        if (e < E_EDGES) {
            const int row = min(max(ei[e], 0), N_NODES - 1);
            const int col = min(max(ei[E_EDGES + e], 0), N_NODES - 1);
            const float v0 = pseudo[2 * e] * 4.0f, v1 = pseudo[2 * e + 1] * 4.0f;
            const float fl0 = floorf(v0), fl1 = floorf(v1);
            const int lo0 = min(max((int)fl0, 0), 3);
            const int lo1 = min(max((int)fl1, 0), 3);
            const int f0q = min((int)((v0 - fl0) * 65536.0f), 65535);
            const int f1q = min((int)((v1 - fl1) * 65536.0f), 65535);
            const int b = lo0 + 4 * lo1;
            rcache[i] = (unsigned long long)row
                      | ((unsigned long long)col << 16)
                      | ((unsigned long long)f0q << 32)
                      | ((unsigned long long)f1q << 48);
            pcache[i]  = b | (atomicAdd(&lh[b], 1) << 8);
            const int cb = row >> 8;
            pcache2[i] = cb | (atomicAdd(&lh2[cb], 1) << 8);
        }
    }
    __syncthreads();

    if (threadIdx.x < NB)
        lbase[threadIdx.x] = atomicAdd(&cursor[threadIdx.x], lh[threadIdx.x]);
    if (threadIdx.x < NCB)
        lbase2[threadIdx.x] = atomicAdd(&cursR[threadIdx.x], lh2[threadIdx.x]);
    __syncthreads();

#pragma unroll
    for (int i = 0; i < EPB; ++i) {
        if (pcache[i] >= 0) {
            const int b = pcache[i] & 0xFF;
            const int idx = min(lbase[b] + (pcache[i] >> 8), BCAP - 1);
            const unsigned recslot = (unsigned)(b * BCAP + idx);
            recs[recslot] = rcache[i];
            const int cb = pcache2[i] & 0xFF;
            const int idx2 = min(lbase2[cb] + (pcache2[i] >> 8), RCAP - 1);
            const unsigned rowlow = (unsigned)(rcache[i] & 0xFF);
            rp[(size_t)cb * RCAP + idx2] = recslot | (rowlow << 20);
        }
    }
}

// per-coarse-bucket 256-bin LDS histogram -> sequential degi write
__global__ __launch_bounds__(256) void deg_hist(
    const unsigned* __restrict__ rp, const int* __restrict__ cursR,
    int* __restrict__ degi)
{
    __shared__ int h[256];
    h[threadIdx.x] = 0;
    __syncthreads();
    const int cb = blockIdx.x;
    const int cnt = min(cursR[cb], RCAP);
    const unsigned* bp = rp + (size_t)cb * RCAP;
    for (int i = threadIdx.x; i < cnt; i += 256)
        atomicAdd(&h[bp[i] >> 20], 1);
    __syncthreads();
    const int row = cb * 256 + threadIdx.x;
    if (row < N_NODES) degi[row] = h[threadIdx.x];
}

// pass B1: per-block local exclusive scan of degi
__global__ __launch_bounds__(1024) void scan_blocks(
    const int* __restrict__ degi, int* __restrict__ rowstart, int* __restrict__ bsum)
{
    __shared__ int wsum[16];
    __shared__ int woff[16];
    const int tid = threadIdx.x, lane = tid & 63, wid = tid >> 6;
    const int n = blockIdx.x * SCANB + tid;
    const int v = (n < N_NODES) ? degi[n] : 0;
    int val = v;
#pragma unroll
    for (int off = 1; off < 64; off <<= 1) {
        int t = __shfl_up(val, off);
        if (lane >= off) val += t;
    }
    if (lane == 63) wsum[wid] = val;
    __syncthreads();
    if (tid == 0) {
        int a = 0;
#pragma unroll
        for (int w = 0; w < 16; ++w) { woff[w] = a; a += wsum[w]; }
        bsum[blockIdx.x] = a;
    }
    __syncthreads();
    if (n < N_NODES) rowstart[n] = woff[wid] + (val - v);
}

// pass B2: each block self-computes its bsum prefix and adds it
__global__ __launch_bounds__(1024) void scan_finish(
    int* __restrict__ rowstart, const int* __restrict__ bsum)
{
    const int b = blockIdx.x;
    int off = 0;
    for (int i = 0; i < NSCANBLK; ++i)
        off += (i < b) ? bsum[i] : 0;
    const int n = b * SCANB + threadIdx.x;
    if (n < N_NODES) rowstart[n] += off;
    if (b == NSCANBLK - 1 && threadIdx.x == 0)
        rowstart[N_NODES] = off + bsum[NSCANBLK - 1];
}

// per-coarse-bucket rank assignment -> eidx permutation (LDS cursors only)
__global__ __launch_bounds__(256) void rank_write(
    const unsigned* __restrict__ rp, const int* __restrict__ cursR,
    const int* __restrict__ rowstart, unsigned* __restrict__ eidx)
{
    __shared__ int cur[256];
    const int cb = blockIdx.x;
    const int row = cb * 256 + threadIdx.x;
    cur[threadIdx.x] = (row < N_NODES) ? rowstart[row] : 0;
    __syncthreads();
    const int cnt = min(cursR[cb], RCAP);
    const unsigned* bp = rp + (size_t)cb * RCAP;
    for (int i = threadIdx.x; i < cnt; i += 256) {
        const unsigned e = bp[i];
        const int pos = min(atomicAdd(&cur[e >> 20], 1), E_EDGES - 1);
        eidx[pos] = e & 0xFFFFF;
    }
}

// pass D: per-cell MFMA, pipelined; msg written SEQUENTIALLY at rec index
// (no rcur/rowstart -- zero scattered atomics; 1/deg via plain degi load)
__global__ __launch_bounds__(256, 2) void bucket_mfma_seq(
    const unsigned short* __restrict__ xbf, const float* __restrict__ weight,
    const unsigned long long* __restrict__ recs,
    const int* __restrict__ cursor, const int* __restrict__ degi,
    unsigned short* __restrict__ msg)
{
    __shared__ short XS[4][16 * KPAD];

    const int lane = threadIdx.x & 63;
    const int wid  = threadIdx.x >> 6;
    const int cell = blockIdx.x & (NB - 1);
    const int wGlob   = (blockIdx.x >> 4) * 4 + wid;
    const int wStride = (gridDim.x >> 4) * 4;
    const int eg = lane >> 2, part = lane & 3;

    const int lo0 = cell & 3, lo1 = cell >> 2;
    const int base = lo0 + 5 * lo1;
    const int offs[4] = {0, 1, 5, 6};
    const int q = lane >> 4;
    const int c = lane & 15;

    s8v bfr[4][4];
#pragma unroll
    for (int s = 0; s < 4; ++s) {
        const float* wp = weight + (size_t)(base + offs[s]) * (CIN * COUT);
#pragma unroll
        for (int nt = 0; nt < 4; ++nt) {
            union { unsigned short u[8]; s8v v; } tmp;
#pragma unroll
            for (int j = 0; j < 8; ++j)
                tmp.u[j] = f2bf(wp[(q * 8 + j) * COUT + nt * 16 + c]);
            bfr[s][nt] = tmp.v;
        }
    }

    const unsigned long long* brec = recs + (size_t)cell * BCAP;
    const int cnt    = min(cursor[cell], BCAP);
    const int ntiles = (cnt + 15) >> 4;   // BCAP = 16*3376 -> stores in-bounds

    int t = wGlob;
    unsigned long long rec_c = 0;
    int deg_c = 1;
    s8v x_c = {};
    if (t < ntiles) {
        rec_c = brec[min(t * 16 + eg, cnt - 1)];
        deg_c = degi[(int)(rec_c & 0xFFFF)];
        x_c = *(const s8v*)(xbf + (size_t)((rec_c >> 16) & 0xFFFF) * CIN + part * 8);
    }

    for (; t < ntiles; t += wStride) {
        const int tn = t + wStride;
        unsigned long long rec_n = 0;
        int deg_n = 1;
        if (tn < ntiles) {
            rec_n = brec[min(tn * 16 + eg, cnt - 1)];
            deg_n = degi[(int)(rec_n & 0xFFFF)];
        }

        const bool vcur = (t * 16 + eg) < cnt;
        const float f0 = (float)(int)((rec_c >> 32) & 0xFFFF) * (1.0f / 65536.0f);
        const float f1 = (float)(int)((rec_c >> 48) & 0xFFFF) * (1.0f / 65536.0f);
        const float invd = vcur ? (1.0f / (float)max(deg_c, 1)) : 0.0f;
        const float s0 = (1.0f - f0) * (1.0f - f1) * invd;
        const float s1 = f0 * (1.0f - f1) * invd;
        const float s2 = (1.0f - f0) * f1 * invd;
        const float s3 = f0 * f1 * invd;

        // stage scaled X' (16 x 128 bf16)
        {
            union { unsigned short u[8]; s8v v; } xin; xin.v = x_c;
            float xv[8];
#pragma unroll
            for (int j = 0; j < 8; ++j) xv[j] = bf2f(xin.u[j]);
            short* dst = &XS[wid][eg * KPAD + part * 8];
            const float ss[4] = {s0, s1, s2, s3};
#pragma unroll
            for (int s = 0; s < 4; ++s) {
                union { unsigned u2[4]; s8v v; } tmp;
#pragma unroll
                for (int j = 0; j < 8; j += 2)
                    tmp.u2[j >> 1] = f2bf2(ss[s] * xv[j], ss[s] * xv[j + 1]);
                *(s8v*)(dst + s * 32) = tmp.v;
            }
        }
        __builtin_amdgcn_wave_barrier();

        s8v afr[4];
        {
            const short* ap = &XS[wid][c * KPAD + q * 8];
#pragma unroll
            for (int ks = 0; ks < 4; ++ks)
                afr[ks] = *(const s8v*)(ap + ks * 32);
        }
        __builtin_amdgcn_wave_barrier();

        // next tile's x gather overlaps MFMA + epilogue
        s8v x_n = {};
        if (tn < ntiles)
            x_n = *(const s8v*)(xbf + (size_t)((rec_n >> 16) & 0xFFFF) * CIN + part * 8);

        f4v acc[4];
#pragma unroll
        for (int nt = 0; nt < 4; ++nt) {
            acc[nt] = (f4v){0.f, 0.f, 0.f, 0.f};
#pragma unroll
            for (int ks = 0; ks < 4; ++ks)
                acc[nt] = __builtin_amdgcn_mfma_f32_16x16x32_bf16(
                    afr[ks], bfr[ks][nt], acc[nt], 0, 0, 0);
        }

        // epilogue: acc -> bf16 tile in LDS -> SEQUENTIAL 2KB tile store
#pragma unroll
        for (int r = 0; r < 4; ++r) {
            const int m = q * 4 + r;
#pragma unroll
            for (int nt = 0; nt < 4; ++nt)
                XS[wid][m * 64 + nt * 16 + c] = (short)f2bf(acc[nt][r]);
        }
        __builtin_amdgcn_wave_barrier();
        {
            const short* sp = &XS[wid][eg * 64 + part * 16];
            s8v vlo = *(const s8v*)sp;
            s8v vhi = *(const s8v*)(sp + 8);
            unsigned short* dst = msg
                + ((size_t)cell * BCAP + (size_t)t * 16 + eg) * COUT + part * 16;
            *(s8v*)dst = vlo;
            *(s8v*)(dst + 8) = vhi;
        }
        __builtin_amdgcn_wave_barrier();

        rec_c = rec_n; deg_c = deg_n; x_c = x_n;
    }
}

// pass E: permuted per-node segment sum + root/bias fuse
__global__ __launch_bounds__(256) void gather_perm(
    const unsigned short* __restrict__ msg, const unsigned* __restrict__ eidx,
    const int* __restrict__ rowstart, const float* __restrict__ x,
    const float* __restrict__ root, const float* __restrict__ bias,
    float* __restrict__ out)
{
    const int wave   = (blockIdx.x * blockDim.x + threadIdx.x) >> 6;
    const int lane   = threadIdx.x & 63;
    const int nwaves = (gridDim.x * blockDim.x) >> 6;

    for (int n = wave; n < N_NODES; n += nwaves) {
        const int s  = rowstart[n];
        const int e2 = rowstart[n + 1];
        float acc = 0.f;
#pragma unroll 8
        for (int p = s; p < e2; ++p) {
            const unsigned slot = eidx[p];            // wave-uniform s_load
            acc += bf2f(msg[(size_t)slot * COUT + lane]);
        }
        const float* xp = x + (size_t)n * CIN;
        float rt = bias[lane];
#pragma unroll
        for (int i = 0; i < CIN; ++i)
            rt += xp[i] * root[i * COUT + lane];
        out[(size_t)n * COUT + lane] = acc + rt;
    }
}

// ================= fallback (R4 atomic) path =================

__global__ __launch_bounds__(256) void count_fb(
    const int* __restrict__ ei, const float* __restrict__ pseudo,
    int* __restrict__ hist, float* __restrict__ deg)
{
    __shared__ int lh[16];
    if (threadIdx.x < 16) lh[threadIdx.x] = 0;
    __syncthreads();
    const int e = blockIdx.x * 256 + threadIdx.x;
    if (e < E_EDGES) {
        int row = min(max(ei[e], 0), N_NODES - 1);
        const float v0 = pseudo[2 * e] * 4.0f, v1 = pseudo[2 * e + 1] * 4.0f;
        const int lo0 = min(max((int)floorf(v0), 0), 3);
        const int lo1 = min(max((int)floorf(v1), 0), 3);
        atomicAdd(&lh[lo0 + 4 * lo1], 1);
        atomicAdd(&deg[row], 1.0f);
    }
    __syncthreads();
    if (threadIdx.x < 16) atomicAdd(&hist[threadIdx.x], lh[threadIdx.x]);
}

__global__ void scan16_fb(const int* __restrict__ hist,
                          int* __restrict__ bstart, int* __restrict__ cursor)
{
    if (threadIdx.x == 0 && blockIdx.x == 0) {
        int acc = 0;
        for (int c = 0; c < 16; ++c) { bstart[c] = acc; cursor[c] = acc; acc += hist[c]; }
    }
}

__global__ __launch_bounds__(256) void scatter_fb(
    const float* __restrict__ pseudo, int* __restrict__ cursor, int* __restrict__ list)
{
    __shared__ int lh[16];
    __shared__ int lbase[16];
    if (threadIdx.x < 16) lh[threadIdx.x] = 0;
    __syncthreads();
    const int e = blockIdx.x * 256 + threadIdx.x;
    int cell = 0, myoff = 0;
    if (e < E_EDGES) {
        const float v0 = pseudo[2 * e] * 4.0f, v1 = pseudo[2 * e + 1] * 4.0f;
        const int lo0 = min(max((int)floorf(v0), 0), 3);
        const int lo1 = min(max((int)floorf(v1), 0), 3);
        cell = lo0 + 4 * lo1;
        myoff = atomicAdd(&lh[cell], 1);
    }
    __syncthreads();
    if (threadIdx.x < 16)
        lbase[threadIdx.x] = atomicAdd(&cursor[threadIdx.x], lh[threadIdx.x]);
    __syncthreads();
    if (e < E_EDGES)
        list[lbase[cell] + myoff] = e;
}

__global__ __launch_bounds__(256, 2) void bucket_mfma_fb(
    const float* __restrict__ x, const int* __restrict__ ei,
    const float* __restrict__ pseudo, const float* __restrict__ weight,
    const int* __restrict__ list, const int* __restrict__ bstart,
    const int* __restrict__ hist, float* __restrict__ out)
{
    __shared__ short XS[4][16 * KPAD];
    const int lane = threadIdx.x & 63;
    const int wid  = threadIdx.x >> 6;
    const int beta = blockIdx.x & 15;
    const int wGlob   = (blockIdx.x >> 4) * 4 + wid;
    const int wStride = (gridDim.x >> 4) * 4;
    const int lo0 = beta & 3, lo1 = beta >> 2;
    const int base = lo0 + 5 * lo1;
    const int offs[4] = {0, 1, 5, 6};
    const int q = lane >> 4, c = lane & 15;

    s8v bfr[4][4];
#pragma unroll
    for (int s = 0; s < 4; ++s) {
        const float* wp = weight + (size_t)(base + offs[s]) * (CIN * COUT);
#pragma unroll
        for (int nt = 0; nt < 4; ++nt) {
            union { unsigned short u[8]; s8v v; } tmp;
#pragma unroll
            for (int j = 0; j < 8; ++j)
                tmp.u[j] = f2bf(wp[(q * 8 + j) * COUT + nt * 16 + c]);
            bfr[s][nt] = tmp.v;
        }
    }
    const int start = bstart[beta], cnt = hist[beta];
    const int ntiles = (cnt + 15) >> 4;

    for (int t = wGlob; t < ntiles; t += wStride) {
        const int ebase = start + t * 16;
        int rowv = 0, colv = 0;
        float b0 = 0.f, b1 = 0.f, b2 = 0.f, b3 = 0.f;
        if (lane < 16 && (t * 16 + lane) < cnt) {
            const int e = list[ebase + lane];
            rowv = min(max(ei[e], 0), N_NODES - 1);
            colv = min(max(ei[E_EDGES + e], 0), N_NODES - 1);
            const float v0 = pseudo[2 * e] * 4.0f, v1 = pseudo[2 * e + 1] * 4.0f;
            const float f0 = v0 - floorf(v0), f1 = v1 - floorf(v1);
            b0 = (1.0f - f0) * (1.0f - f1);
            b1 = f0 * (1.0f - f1);
            b2 = (1.0f - f0) * f1;
            b3 = f0 * f1;
        }
        {
            const int eg = lane >> 2, part = lane & 3;
            const int  gc = __shfl(colv, eg);
            const float ss0 = __shfl(b0, eg), ss1 = __shfl(b1, eg);
            const float ss2 = __shfl(b2, eg), ss3 = __shfl(b3, eg);
            const float ss[4] = {ss0, ss1, ss2, ss3};
            const float* xp = x + (size_t)gc * CIN + part * 8;
            float xv[8];
            *(f4v*)&xv[0] = *(const f4v*)xp;
            *(f4v*)&xv[4] = *(const f4v*)(xp + 4);
            short* dst = &XS[wid][eg * KPAD + part * 8];
#pragma unroll
            for (int s = 0; s < 4; ++s) {
                union { unsigned short u[8]; s8v v; } tmp;
#pragma unroll
                for (int j = 0; j < 8; ++j)
                    tmp.u[j] = f2bf(ss[s] * xv[j]);
                *(s8v*)(dst + s * 32) = tmp.v;
            }
        }
        __builtin_amdgcn_wave_barrier();
        s8v afr[4];
        {
            const short* ap = &XS[wid][c * KPAD + q * 8];
#pragma unroll
            for (int ks = 0; ks < 4; ++ks)
                afr[ks] = *(const s8v*)(ap + ks * 32);
        }
        __builtin_amdgcn_wave_barrier();
        f4v acc[4];
#pragma unroll
        for (int nt = 0; nt < 4; ++nt) {
            acc[nt] = (f4v){0.f, 0.f, 0.f, 0.f};
#pragma unroll
            for (int ks = 0; ks < 4; ++ks)
                acc[nt] = __builtin_amdgcn_mfma_f32_16x16x32_bf16(
                    afr[ks], bfr[ks][nt], acc[nt], 0, 0, 0);
        }
#pragma unroll
        for (int r = 0; r < 4; ++r) {
            const int m = q * 4 + r;
            const int orow = __shfl(rowv, m);
#pragma unroll
            for (int nt = 0; nt < 4; ++nt)
                atomicAdd(&out[(size_t)orow * COUT + nt * 16 + c], acc[nt][r]);
        }
    }
}

__global__ __launch_bounds__(256) void final_fb(
    const float* __restrict__ x, const float* __restrict__ root,
    const float* __restrict__ bias, const float* __restrict__ deg,
    float* __restrict__ out)
{
    const int wave   = (blockIdx.x * blockDim.x + threadIdx.x) >> 6;
    const int lane   = threadIdx.x & 63;
    const int nwaves = (gridDim.x * blockDim.x) >> 6;
    for (int n = wave; n < N_NODES; n += nwaves) {
        const float* xp = x + (size_t)n * CIN;
        float acc = bias[lane];
#pragma unroll
        for (int i = 0; i < CIN; ++i)
            acc += xp[i] * root[i * COUT + lane];
        float dg = deg[n];
        dg = dg > 1.0f ? dg : 1.0f;
        const size_t idx = (size_t)n * COUT + lane;
        out[idx] = out[idx] / dg + acc;
    }
}

extern "C" void kernel_launch(void* const* d_in, const int* in_sizes, int n_in,
                              void* d_out, int out_size, void* d_ws, size_t ws_size,
                              hipStream_t stream) {
    const float* x      = (const float*)d_in[0];
    const int*   ei     = (const int*)d_in[1];
    const float* pseudo = (const float*)d_in[2];
    const float* weight = (const float*)d_in[3];
    const float* root   = (const float*)d_in[4];
    const float* bias   = (const float*)d_in[5];
    float* out = (float*)d_out;

    // ws layout (int elements)
    int* wsI = (int*)d_ws;
    int* cursor16 = wsI;                         // 16 (+16 pad)
    int* cursR    = wsI + 32;                    // 196 (+28 pad) -> 224
    int* degi     = wsI + 256;                   // 50000
    int* rowstart = wsI + 50256;                 // 50001 (+15 pad)
    int* bsum     = wsI + 100272;                // 64 (+16 pad) -> 100352 ints total
    // byte offsets from 100352*4 = 401408
    unsigned long long* recs = (unsigned long long*)((char*)d_ws + 401408);   // 6.91 MB
    unsigned* rp   = (unsigned*)((char*)d_ws + 401408 + (size_t)NB * BCAP * 8);       // 3.81 MB
    unsigned* eidx = (unsigned*)((char*)rp + (size_t)NCB * RCAP * 4);                  // 3.2 MB
    unsigned short* xbf = (unsigned short*)((char*)eidx + (size_t)E_EDGES * 4);        // 3.2 MB
    unsigned short* msg = (unsigned short*)((char*)xbf + (size_t)N_NODES * CIN * 2);   // 110.6 MB
    const size_t needed = 401408 + (size_t)NB * BCAP * 8 + (size_t)NCB * RCAP * 4
                        + (size_t)E_EDGES * 4 + (size_t)N_NODES * CIN * 2
                        + (size_t)NB * BCAP * COUT * 2;   // ~128.2 MB

    if (ws_size >= needed) {
        (void)hipMemsetAsync(d_ws, 0, 256 * 4, stream);   // cursor16 + cursR only
        build_recs <<<BBLK, 256, 0, stream>>>(x, xbf, ei, pseudo, cursor16, cursR, recs, rp);
        deg_hist   <<<NCB, 256, 0, stream>>>(rp, cursR, degi);
        scan_blocks<<<NSCANBLK, 1024, 0, stream>>>(degi, rowstart, bsum);
        scan_finish<<<NSCANBLK, 1024, 0, stream>>>(rowstart, bsum);
        rank_write <<<NCB, 256, 0, stream>>>(rp, cursR, rowstart, eidx);
        bucket_mfma_seq<<<16 * 128, 256, 0, stream>>>(
            xbf, weight, recs, cursor16, degi, msg);
        gather_perm<<<4096, 256, 0, stream>>>(msg, eidx, rowstart, x, root, bias, out);
    } else {
        // R4 fallback layout
        char* w = (char*)d_ws;
        float* degF   = (float*)w;
        int*   histF  = (int*)(w + 200064);
        int*   bstF   = (int*)(w + 200128);
        int*   curF   = (int*)(w + 200192);
        int*   listF  = (int*)(w + 200256);
        const int eblocks = (E_EDGES + 255) / 256;

        (void)hipMemsetAsync(out, 0, sizeof(float) * (size_t)N_NODES * COUT, stream);
        (void)hipMemsetAsync(degF, 0, sizeof(float) * (size_t)N_NODES, stream);
        (void)hipMemsetAsync(histF, 0, 192, stream);

        count_fb      <<<eblocks, 256, 0, stream>>>(ei, pseudo, histF, degF);
        scan16_fb     <<<1, 64, 0, stream>>>(histF, bstF, curF);
        scatter_fb    <<<eblocks, 256, 0, stream>>>(pseudo, curF, listF);
        bucket_mfma_fb<<<16 * 64, 256, 0, stream>>>(x, ei, pseudo, weight, listF,
                                                    bstF, histF, out);
        final_fb      <<<1024, 256, 0, stream>>>(x, root, bias, degF, out);
    }
}